// Round 13
// baseline (869.489 us; speedup 1.0000x reference)
//
#include <hip/hip_runtime.h>
#include <hip/hip_bf16.h>

typedef unsigned short u16;
typedef __attribute__((ext_vector_type(8))) short bf16x8;
typedef __attribute__((ext_vector_type(4))) float f32x4;
typedef __attribute__((ext_vector_type(4))) float vfloat4;
typedef __attribute__((ext_vector_type(4))) unsigned short ushort4v;
typedef __attribute__((ext_vector_type(8))) unsigned short ushort8v;

#define DEV __device__ __forceinline__
#define AS1 __attribute__((address_space(1)))
#define AS3 __attribute__((address_space(3)))

#define BARRIER()  __builtin_amdgcn_s_barrier()
#define LGKM0()    asm volatile("s_waitcnt lgkmcnt(0)" ::: "memory")
#define VMCNT0()   asm volatile("s_waitcnt vmcnt(0)" ::: "memory")
#define VMCNT2()   asm volatile("s_waitcnt vmcnt(2)" ::: "memory")
#define SCHED0()   __builtin_amdgcn_sched_barrier(0)

DEV u16 f2bf(float f) {
    union { float f; unsigned u; } v; v.f = f;
    unsigned r = v.u + 0x7FFFu + ((v.u >> 16) & 1u);
    return (u16)(r >> 16);
}

DEV short f2bf_hw(float f) {
    __hip_bfloat16 h = __float2bfloat16(f);
    short s;
    __builtin_memcpy(&s, &h, 2);
    return s;
}

DEV void gload_lds16(const void* g, void* l) {
    __builtin_amdgcn_global_load_lds((const AS1 unsigned int*)g,
                                     (AS3 unsigned int*)l, 16, 0, 0);
}

static constexpr int KDIM = 1024;   // embed
static constexpr int NROW = 65536;  // B*S

// ---------------- fp32 -> bf16 convert (for the small W matrices) -----------
__global__ __launch_bounds__(256)
void cvt_f32_bf16(const float* __restrict__ src, u16* __restrict__ dst, unsigned n8)
{
    unsigned stride = gridDim.x * blockDim.x;
    for (unsigned i = blockIdx.x * blockDim.x + threadIdx.x; i < n8; i += stride) {
        size_t base = (size_t)i * 8;
        vfloat4 a = *(const vfloat4*)(src + base);
        vfloat4 b = *(const vfloat4*)(src + base + 4);
        ushort8v o;
#pragma unroll
        for (int j = 0; j < 4; ++j) { o[j] = f2bf(a[j]); o[j + 4] = f2bf(b[j]); }
        *(ushort8v*)(dst + base) = o;
    }
}

// ---------------- fused 4-phase 256^2 GEMM, fp32-A in LDS --------------------
// Y = f2bf(X) @ Wb^T + b.  X fp32 [65536,1024], Wb bf16.  BM=BN=256, BK=32,
// 32 K-tiles, 8 waves (2Mx4N), acc[8][4].  A staged as FP32 via global_load_lds
// (no register staging -> no r5-style spill); converted to bf16 AFTER ds_read,
// between LGKM0 and MFMA (compiler emits v_cvt_pk_bf16_f32).  This deletes the
// 3x 65us cvt-X passes (their 402MB/projection HBM round trip).
// LDS: Asf[2][256*32]f32 (64KB) + Bs[2][256*32]bf16 (32KB) = 96KB.
// Swizzles (involutions, verified): A granule(16B) ^= row&7 (8 granules/row,
// 2-way on read = free); B granule ^= row&3 (4 granules/row, 4-way on the 4
// B-reads/K-tile, minor).
// Ledger (STAGE_A=4 gloads, STAGE_B=2; vmcnt(2) at M2/M4 close):
//   M1: read s0 A-lo + all B(s0); stage As1(c12)       [outst 2->6]
//   M2: read s0 A-hi; stage Bs0(c36); vmcnt(2)         [drains Bs1'+As1 -> M3 ok]
//   M3: read s1 A-lo + all B(s1); stage As0(c36)       [outst 2->6]
//   M4: read s1 A-hi; stage Bs1(c78); vmcnt(2)         [drains Bs0+As0 -> M1' ok]
// Overwrite windows: every region staged >=1 barrier after its last read
// retired (LGKM0 pins read retirement before each phase's close barrier).
__global__ __launch_bounds__(512)
__attribute__((amdgpu_waves_per_eu(1, 2)))
void proj_gemm_8ph(const float* __restrict__ X, const u16* __restrict__ W,
                   const float* __restrict__ bias, u16* __restrict__ Y)
{
    __shared__ __align__(16) float Asf[2][256 * 32];   // 64 KB
    __shared__ __align__(16) u16   Bs[2][256 * 32];    // 32 KB

    int bx = blockIdx.x;                  // 0..1023
    int wg = (bx & 7) * 128 + (bx >> 3);  // XCD-chunked swizzle (1024 % 8 == 0)
    int bm = wg >> 2;                     // 0..255
    int bn = wg & 3;                      // 0..3

    int tid  = threadIdx.x;
    int lane = tid & 63;
    int wid  = tid >> 6;       // 0..7
    int wm   = wid >> 2;       // 0..1
    int wn   = wid & 3;        // 0..3
    int l15  = lane & 15;
    int l4   = lane >> 4;

    const float* Xp = X + (size_t)bm * 256 * KDIM;
    const u16*   Wp = W + (size_t)bn * 256 * KDIM;

    // A staging: lane covers (row = tid>>3 in 0..63 per issue-block, granule =
    // tid&7 of 8x16B per 128B row); source granule pre-XOR'd with row&7.
    int arow = tid >> 3;
    int ags  = (tid & 7) ^ (arow & 7);
    // B staging: 64B rows, 4 granules; lane covers (row = tid>>2, granule tid&3)
    int brow = tid >> 2;
    int bgs  = (tid & 3) ^ (brow & 3);

    f32x4 acc[8][4] = {};

#define STAGE_A(slot, kt)                                                        \
    {                                                                            \
        _Pragma("unroll")                                                        \
        for (int j = 0; j < 4; ++j)                                              \
            gload_lds16(Xp + (size_t)(j * 64 + arow) * KDIM + (kt) * 32 + ags * 4, \
                        &Asf[slot][(j * 64 + wid * 8) * 32]);                    \
    }

#define STAGE_B(slot, kt)                                                        \
    {                                                                            \
        _Pragma("unroll")                                                        \
        for (int j = 0; j < 2; ++j)                                              \
            gload_lds16(Wp + (size_t)(j * 128 + brow) * KDIM + (kt) * 32 + bgs * 8, \
                        &Bs[slot][(j * 128 + wid * 16) * 32]);                   \
    }

#define READ_A_LOAD(slot, mh)                                                    \
    {                                                                            \
        _Pragma("unroll")                                                        \
        for (int mi = 0; mi < 4; ++mi) {                                         \
            int row = wm * 128 + (mh) * 64 + mi * 16 + l15;                      \
            unsigned g0 = (unsigned)((2 * l4)     ^ (row & 7));                  \
            unsigned g1 = (unsigned)((2 * l4 + 1) ^ (row & 7));                  \
            ar[mi][0] = *(const f32x4*)((const char*)Asf[slot] + row * 128 + g0 * 16); \
            ar[mi][1] = *(const f32x4*)((const char*)Asf[slot] + row * 128 + g1 * 16); \
        }                                                                        \
    }

#define CVT_AF()                                                                 \
    {                                                                            \
        _Pragma("unroll")                                                        \
        for (int mi = 0; mi < 4; ++mi) {                                         \
            bf16x8 v;                                                            \
            _Pragma("unroll")                                                    \
            for (int e = 0; e < 4; ++e) {                                        \
                v[e]     = f2bf_hw(ar[mi][0][e]);                                \
                v[e + 4] = f2bf_hw(ar[mi][1][e]);                                \
            }                                                                    \
            af[mi] = v;                                                          \
        }                                                                        \
    }

#define READ_BF(dst, slot, nlo)                                                  \
    {                                                                            \
        _Pragma("unroll")                                                        \
        for (int ni = 0; ni < 2; ++ni) {                                         \
            int row = wn * 64 + ((nlo) + ni) * 16 + l15;                         \
            dst[ni] = *(const bf16x8*)((const char*)Bs[slot] + row * 64          \
                        + ((unsigned)(l4 ^ (row & 3)) << 4));                    \
        }                                                                        \
    }

#define MFMA_Q8(mlo, bb, nlo)                                                    \
    __builtin_amdgcn_s_setprio(1);                                               \
    _Pragma("unroll")                                                            \
    for (int mi = 0; mi < 4; ++mi) {                                             \
        _Pragma("unroll")                                                        \
        for (int ni = 0; ni < 2; ++ni)                                           \
            acc[(mlo) + mi][(nlo) + ni] = __builtin_amdgcn_mfma_f32_16x16x32_bf16( \
                af[mi], bb[ni], acc[(mlo) + mi][(nlo) + ni], 0, 0, 0);           \
    }                                                                            \
    __builtin_amdgcn_s_setprio(0);

    // ---- prologue: kt0 -> slot0, kt1 -> slot1, full drain
    STAGE_A(0, 0);
    STAGE_B(0, 0);
    STAGE_A(1, 1);
    STAGE_B(1, 1);
    VMCNT0();
    BARRIER();

    // ---- main loop: 16 iterations x 2 K-tiles, 4 merged phases each
    for (int it = 0; it < 16; ++it) {
        int c12 = 2 * it + 1;
        int c36 = (2 * it + 2 < 32) ? 2 * it + 2 : 31;
        int c78 = (2 * it + 3 < 32) ? 2 * it + 3 : 31;
        f32x4 ar[4][2];
        bf16x8 af[4], b0[2], b1[2];

        // M1: read s0 A-lo + all B(s0); stage As1(c12)
        READ_A_LOAD(0, 0); READ_BF(b0, 0, 0); READ_BF(b1, 0, 2);
        STAGE_A(1, c12);
        BARRIER(); LGKM0(); SCHED0();
        CVT_AF();
        MFMA_Q8(0, b0, 0); MFMA_Q8(0, b1, 2);
        BARRIER();

        // M2: read s0 A-hi; stage Bs0(c36); vmcnt(2) drains Bs1'+As1 for M3
        READ_A_LOAD(0, 1);
        STAGE_B(0, c36);
        VMCNT2(); BARRIER(); LGKM0(); SCHED0();
        CVT_AF();
        MFMA_Q8(4, b0, 0); MFMA_Q8(4, b1, 2);
        BARRIER();

        // M3: read s1 A-lo + all B(s1); stage As0(c36)
        READ_A_LOAD(1, 0); READ_BF(b0, 1, 0); READ_BF(b1, 1, 2);
        STAGE_A(0, c36);
        BARRIER(); LGKM0(); SCHED0();
        CVT_AF();
        MFMA_Q8(0, b0, 0); MFMA_Q8(0, b1, 2);
        BARRIER();

        // M4: read s1 A-hi; stage Bs1(c78); vmcnt(2) drains Bs0+As0 for M1'
        READ_A_LOAD(1, 1);
        STAGE_B(1, c78);
        VMCNT2(); BARRIER(); LGKM0(); SCHED0();
        CVT_AF();
        MFMA_Q8(4, b0, 0); MFMA_Q8(4, b1, 2);
        BARRIER();
    }
    VMCNT0();
    BARRIER();  // all staging landed, all reads done -> LDS reusable as C-tile

    // ---- coalesced epilogue through LDS (reuses Asf = 64KB as [128][256] u16)
    u16* Cs = (u16*)&Asf[0][0];
#pragma unroll
    for (int p = 0; p < 2; ++p) {
        if (wm == p) {
#pragma unroll
            for (int ni = 0; ni < 4; ++ni) {
                float bv = bias[bn * 256 + wn * 64 + ni * 16 + l15];
#pragma unroll
                for (int mi = 0; mi < 8; ++mi) {
                    int c2 = (wn * 64 + ni * 16 + l15) * 2;
#pragma unroll
                    for (int r = 0; r < 4; ++r) {
                        int row = mi * 16 + l4 * 4 + r;
                        unsigned off = (unsigned)(row * 512 + c2) ^ (unsigned)((row & 7) << 4);
                        *(u16*)((char*)Cs + off) = f2bf(acc[mi][ni][r] + bv);
                    }
                }
            }
        }
        __syncthreads();
#pragma unroll
        for (int i = 0; i < 8; ++i) {
            int idx = tid + i * 512;          // 0..4095
            int row = idx >> 5;               // 0..127
            int c16 = idx & 31;               // 16B chunk
            unsigned off = (unsigned)(row * 512 + c16 * 16) ^ (unsigned)((row & 7) << 4);
            ushort8v v = *(const ushort8v*)((const char*)Cs + off);
            *(ushort8v*)&Y[(size_t)(bm * 256 + p * 128 + row) * KDIM
                           + bn * 256 + c16 * 8] = v;
        }
        __syncthreads();
    }
#undef STAGE_A
#undef STAGE_B
#undef READ_A_LOAD
#undef CVT_AF
#undef READ_BF
#undef MFMA_Q8
}

// ---------------- Fallback: fp32 in, convert in-loop (128^2, 2-barrier) -----
__global__ __launch_bounds__(256)
void proj_gemm(const float* __restrict__ X, const float* __restrict__ W,
               const float* __restrict__ bias, u16* __restrict__ Y)
{
    __shared__ u16 As[128 * 64];
    __shared__ u16 Bs[128 * 64];

    int bx = blockIdx.x;
    int wg = (bx & 7) * 512 + (bx >> 3);
    int bm = wg >> 3;
    int bn = wg & 7;

    int tid  = threadIdx.x;
    int lane = tid & 63;
    int wid  = tid >> 6;
    int wrow = (wid >> 1) * 64;
    int wcol = (wid & 1) * 64;
    int l15 = lane & 15;
    int l4  = lane >> 4;

    int srow = tid >> 4;
    int scol = (tid & 15) * 4;

    const float* Xp = X + (size_t)bm * 128 * KDIM;
    const float* Wp = W + (size_t)bn * 128 * KDIM;

    f32x4 acc[4][4] = {};

    for (int k0 = 0; k0 < KDIM; k0 += 64) {
        __syncthreads();
#pragma unroll
        for (int r = 0; r < 8; ++r) {
            int row = r * 16 + srow;
            vfloat4 a = *(const vfloat4*)(Xp + (size_t)row * KDIM + k0 + scol);
            vfloat4 b = *(const vfloat4*)(Wp + (size_t)row * KDIM + k0 + scol);
            ushort4v ap, bp;
#pragma unroll
            for (int j = 0; j < 4; ++j) { ap[j] = f2bf(a[j]); bp[j] = f2bf(b[j]); }
            unsigned off = (unsigned)(row * 128 + scol * 2) ^ (unsigned)((row & 7) << 4);
            *(ushort4v*)((char*)As + off) = ap;
            *(ushort4v*)((char*)Bs + off) = bp;
        }
        __syncthreads();
#pragma unroll
        for (int kk = 0; kk < 2; ++kk) {
            bf16x8 af[4], bfr[4];
#pragma unroll
            for (int mi = 0; mi < 4; ++mi) {
                int row = wrow + mi * 16 + l15;
                unsigned off = (unsigned)(row * 128 + kk * 64 + l4 * 16) ^ (unsigned)((row & 7) << 4);
                af[mi] = *(const bf16x8*)((char*)As + off);
            }
#pragma unroll
            for (int ni = 0; ni < 4; ++ni) {
                int row = wcol + ni * 16 + l15;
                unsigned off = (unsigned)(row * 128 + kk * 64 + l4 * 16) ^ (unsigned)((row & 7) << 4);
                bfr[ni] = *(const bf16x8*)((char*)Bs + off);
            }
#pragma unroll
            for (int mi = 0; mi < 4; ++mi)
#pragma unroll
                for (int ni = 0; ni < 4; ++ni)
                    acc[mi][ni] = __builtin_amdgcn_mfma_f32_16x16x32_bf16(
                        af[mi], bfr[ni], acc[mi][ni], 0, 0, 0);
        }
    }

#pragma unroll
    for (int ni = 0; ni < 4; ++ni) {
        int col = bn * 128 + wcol + ni * 16 + l15;
        float bv = bias[col];
#pragma unroll
        for (int mi = 0; mi < 4; ++mi) {
            int row0 = bm * 128 + wrow + mi * 16 + l4 * 4;
#pragma unroll
            for (int r = 0; r < 4; ++r)
                Y[(size_t)(row0 + r) * KDIM + col] = f2bf(acc[mi][ni][r] + bv);
        }
    }
}

// ---------------- Pass 2: grouped attention ----------------
__global__ __launch_bounds__(256)
void attn_kernel(const u16* __restrict__ Qg, const u16* __restrict__ Kg,
                 const u16* __restrict__ Vg, float* __restrict__ Out)
{
    __shared__ u16 Qs[128 * 64];     // [q][d] swizzled
    __shared__ u16 KVs[64 * 136];    // union: Ks [128][64] swizzled / Vt [64][136]
    __shared__ u16 Ps[128 * 136];    // [q][k], row stride 136

    int g = blockIdx.x >> 4;
    int h = blockIdx.x & 15;

    int tid  = threadIdx.x;
    int lane = tid & 63;
    int wid  = tid >> 6;
    int l15 = lane & 15, l4 = lane >> 4;
    int qbase = wid * 32;

    size_t rowbase = (size_t)g * 128 * 1024 + (size_t)h * 64;

    {
        int r  = tid >> 1;
        int c0 = (tid & 1) * 32;
        const u16* qsrc = Qg + rowbase + (size_t)r * 1024 + c0;
        const u16* ksrc = Kg + rowbase + (size_t)r * 1024 + c0;
#pragma unroll
        for (int i = 0; i < 4; ++i) {
            ushort8v qv = *(const ushort8v*)(qsrc + i * 8);
            ushort8v kv = *(const ushort8v*)(ksrc + i * 8);
            unsigned off = (unsigned)(r * 128 + (c0 + i * 8) * 2) ^ (unsigned)((r & 7) << 4);
            *(ushort8v*)((char*)Qs + off) = qv;
            *(ushort8v*)((char*)KVs + off) = kv;
        }
    }
    __syncthreads();

    f32x4 st[8][2] = {};
#pragma unroll
    for (int kk = 0; kk < 2; ++kk) {
        bf16x8 kf[8];
#pragma unroll
        for (int mi = 0; mi < 8; ++mi) {
            int row = mi * 16 + l15;
            unsigned off = (unsigned)(row * 128 + kk * 64 + l4 * 16) ^ (unsigned)((row & 7) << 4);
            kf[mi] = *(const bf16x8*)((char*)KVs + off);
        }
#pragma unroll
        for (int qi = 0; qi < 2; ++qi) {
            int row = qbase + qi * 16 + l15;
            unsigned off = (unsigned)(row * 128 + kk * 64 + l4 * 16) ^ (unsigned)((row & 7) << 4);
            bf16x8 qf = *(const bf16x8*)((char*)Qs + off);
#pragma unroll
            for (int mi = 0; mi < 8; ++mi)
                st[mi][qi] = __builtin_amdgcn_mfma_f32_16x16x32_bf16(kf[mi], qf, st[mi][qi], 0, 0, 0);
        }
    }
    __syncthreads();

    {
        int r  = tid >> 1;
        int c0 = (tid & 1) * 32;
        const u16* vsrc = Vg + rowbase + (size_t)r * 1024 + c0;
#pragma unroll
        for (int i = 0; i < 4; ++i) {
            ushort8v vv = *(const ushort8v*)(vsrc + i * 8);
#pragma unroll
            for (int e = 0; e < 8; ++e)
                KVs[(c0 + i * 8 + e) * 136 + r] = vv[e];
        }
    }

    const float cexp = 0.125f * 1.44269504088896f;
#pragma unroll
    for (int qi = 0; qi < 2; ++qi) {
        float m = -3.0e38f;
#pragma unroll
        for (int mi = 0; mi < 8; ++mi)
#pragma unroll
            for (int r = 0; r < 4; ++r) m = fmaxf(m, st[mi][qi][r]);
        m = fmaxf(m, __shfl_xor(m, 16));
        m = fmaxf(m, __shfl_xor(m, 32));
        float s = 0.f;
#pragma unroll
        for (int mi = 0; mi < 8; ++mi)
#pragma unroll
            for (int r = 0; r < 4; ++r) {
                float p = exp2f((st[mi][qi][r] - m) * cexp);
                st[mi][qi][r] = p;
                s += p;
            }
        s += __shfl_xor(s, 16);
        s += __shfl_xor(s, 32);
        float inv = 1.0f / s;
        int q = qbase + qi * 16 + l15;
#pragma unroll
        for (int mi = 0; mi < 8; ++mi) {
            ushort4v pp;
#pragma unroll
            for (int r = 0; r < 4; ++r) pp[r] = f2bf(st[mi][qi][r] * inv);
            *(ushort4v*)((char*)Ps + (unsigned)(q * 272 + mi * 32 + l4 * 8)) = pp;
        }
    }
    __syncthreads();

    f32x4 o[2][4] = {};
#pragma unroll
    for (int kk = 0; kk < 4; ++kk) {
        bf16x8 pa[2];
#pragma unroll
        for (int mf = 0; mf < 2; ++mf) {
            int q = qbase + mf * 16 + l15;
            pa[mf] = *(const bf16x8*)((char*)Ps + (unsigned)(q * 272 + kk * 64 + l4 * 16));
        }
#pragma unroll
        for (int nf = 0; nf < 4; ++nf) {
            int d = nf * 16 + l15;
            bf16x8 vb = *(const bf16x8*)((char*)KVs + (unsigned)(d * 272 + kk * 64 + l4 * 16));
#pragma unroll
            for (int mf = 0; mf < 2; ++mf)
                o[mf][nf] = __builtin_amdgcn_mfma_f32_16x16x32_bf16(pa[mf], vb, o[mf][nf], 0, 0, 0);
        }
    }

#pragma unroll
    for (int mf = 0; mf < 2; ++mf)
#pragma unroll
        for (int nf = 0; nf < 4; ++nf) {
            int d  = nf * 16 + l15;
            int q0 = qbase + mf * 16 + l4 * 4;
#pragma unroll
            for (int r = 0; r < 4; ++r)
                Out[(size_t)(g * 128 + q0 + r) * 1024 + h * 64 + d] = o[mf][nf][r];
        }
}

extern "C" void kernel_launch(void* const* d_in, const int* in_sizes, int n_in,
                              void* d_out, int out_size, void* d_ws, size_t ws_size,
                              hipStream_t stream)
{
    const float* Xq = (const float*)d_in[0];
    const float* Xk = (const float*)d_in[1];
    const float* Xv = (const float*)d_in[2];
    const float* Wq = (const float*)d_in[3];
    const float* bq = (const float*)d_in[4];
    const float* Wk = (const float*)d_in[5];
    const float* bk = (const float*)d_in[6];
    const float* Wv = (const float*)d_in[7];
    const float* bv = (const float*)d_in[8];

    const size_t NE = (size_t)NROW * KDIM;       // 67,108,864
    const size_t WE = (size_t)KDIM * KDIM;       // 1,048,576

    u16* Qw = (u16*)d_ws;
    u16* Kw = Qw + NE;
    u16* Vw = Kw + NE;

    size_t need = NE * 2 * 3 + WE * 2 * 3;       // QKV bf16 + 3 W bf16 (no Xb)

    if (ws_size >= need) {
        u16* Wb0 = Vw + NE;
        u16* Wb1 = Wb0 + WE;
        u16* Wb2 = Wb1 + WE;

        cvt_f32_bf16<<<dim3(512), dim3(256), 0, stream>>>(Wq, Wb0, (unsigned)(WE / 8));
        cvt_f32_bf16<<<dim3(512), dim3(256), 0, stream>>>(Wk, Wb1, (unsigned)(WE / 8));
        cvt_f32_bf16<<<dim3(512), dim3(256), 0, stream>>>(Wv, Wb2, (unsigned)(WE / 8));

        proj_gemm_8ph<<<dim3(1024), dim3(512), 0, stream>>>(Xq, Wb0, bq, Qw);
        proj_gemm_8ph<<<dim3(1024), dim3(512), 0, stream>>>(Xk, Wb1, bk, Kw);
        proj_gemm_8ph<<<dim3(1024), dim3(512), 0, stream>>>(Xv, Wb2, bv, Vw);
    } else {
        proj_gemm<<<dim3(4096), dim3(256), 0, stream>>>(Xq, Wq, bq, Qw);
        proj_gemm<<<dim3(4096), dim3(256), 0, stream>>>(Xk, Wk, bk, Kw);
        proj_gemm<<<dim3(4096), dim3(256), 0, stream>>>(Xv, Wv, bv, Vw);
    }

    attn_kernel<<<dim3(512 * 16), dim3(256), 0, stream>>>(Qw, Kw, Vw, (float*)d_out);
}

// Round 14
// 843.409 us; speedup vs baseline: 1.0309x; 1.0309x over previous
//
#include <hip/hip_runtime.h>
#include <hip/hip_bf16.h>

typedef unsigned short u16;
typedef __attribute__((ext_vector_type(8))) short bf16x8;
typedef __attribute__((ext_vector_type(4))) float f32x4;
typedef __attribute__((ext_vector_type(4))) float vfloat4;
typedef __attribute__((ext_vector_type(4))) unsigned short ushort4v;
typedef __attribute__((ext_vector_type(8))) unsigned short ushort8v;

#define DEV __device__ __forceinline__
#define AS1 __attribute__((address_space(1)))
#define AS3 __attribute__((address_space(3)))

#define BARRIER()  __builtin_amdgcn_s_barrier()
#define LGKM0()    asm volatile("s_waitcnt lgkmcnt(0)" ::: "memory")
#define VMCNT0()   asm volatile("s_waitcnt vmcnt(0)" ::: "memory")
#define VMCNT4()   asm volatile("s_waitcnt vmcnt(4)" ::: "memory")
#define SCHED0()   __builtin_amdgcn_sched_barrier(0)

DEV u16 f2bf(float f) {
    union { float f; unsigned u; } v; v.f = f;
    unsigned r = v.u + 0x7FFFu + ((v.u >> 16) & 1u);
    return (u16)(r >> 16);
}

DEV void gload_lds16(const void* g, void* l) {
    __builtin_amdgcn_global_load_lds((const AS1 unsigned int*)g,
                                     (AS3 unsigned int*)l, 16, 0, 0);
}

static constexpr int KDIM = 1024;   // embed
static constexpr int NROW = 65536;  // B*S

// ---------------- fp32 -> bf16 convert (memory-bound) ----------------
__global__ __launch_bounds__(256)
void cvt_f32_bf16(const float* __restrict__ src, u16* __restrict__ dst, unsigned n8)
{
    unsigned stride = gridDim.x * blockDim.x;
    for (unsigned i = blockIdx.x * blockDim.x + threadIdx.x; i < n8; i += stride) {
        size_t base = (size_t)i * 8;
        vfloat4 a = *(const vfloat4*)(src + base);
        vfloat4 b = *(const vfloat4*)(src + base + 4);
        ushort8v o;
#pragma unroll
        for (int j = 0; j < 4; ++j) { o[j] = f2bf(a[j]); o[j + 4] = f2bf(b[j]); }
        *(ushort8v*)(dst + base) = o;
    }
}

// ---------------- 8-phase 256^2 bf16 GEMM (round-11 proven core) -------------
// Y = Xb @ Wb^T + b, all bf16. BM=BN=256, BK=64, 16 K-tiles, 8 waves (2Mx4N).
// Full-slot ledger, vmcnt(4) at P4/P8, kk-outermost MFMA (8-way independent
// bursts), coalesced LDS-staged epilogue (WRITE_SIZE == Y bytes exactly).
// NEW: optional grid-stride fp32->bf16 tail converting the NEXT projection's
// X while this GEMM's block-tail drains — hides the 65us cvt pass under the
// GEMM's idle HBM bandwidth (GEMM runs at only ~1.5 of 6.3 TB/s).
__global__ __launch_bounds__(512)
__attribute__((amdgpu_waves_per_eu(1, 2)))
void proj_gemm_8ph(const u16* __restrict__ X, const u16* __restrict__ W,
                   const float* __restrict__ bias, u16* __restrict__ Y,
                   const float* __restrict__ Xnext, u16* __restrict__ Xbnext)
{
    __shared__ __align__(16) u16 As[2][256 * 64];
    __shared__ __align__(16) u16 Bs[2][256 * 64];

    int bx = blockIdx.x;                  // 0..1023
    int wg = (bx & 7) * 128 + (bx >> 3);  // XCD-chunked swizzle (1024 % 8 == 0)
    int bm = wg >> 2;                     // 0..255
    int bn = wg & 3;                      // 0..3

    int tid  = threadIdx.x;
    int lane = tid & 63;
    int wid  = tid >> 6;       // 0..7
    int wm   = wid >> 2;       // 0..1
    int wn   = wid & 3;        // 0..3
    int l15  = lane & 15;
    int l4   = lane >> 4;

    const u16* Xp = X + (size_t)bm * 256 * KDIM;
    const u16* Wp = W + (size_t)bn * 256 * KDIM;

    int srow_in = tid >> 3;
    int scol16  = (tid & 7) ^ (srow_in & 7);

    f32x4 acc[8][4] = {};

#define STAGE(lds, gbase, slot, h, kt)                                           \
    {                                                                            \
        const u16* src_ = (gbase) + (size_t)((h) * 128 + srow_in) * KDIM         \
                          + (kt) * 64 + scol16 * 8;                              \
        gload_lds16(src_, &lds[slot][((h) * 128 + wid * 8) * 64]);               \
        gload_lds16(src_ + (size_t)64 * KDIM,                                    \
                    &lds[slot][((h) * 128 + 64 + wid * 8) * 64]);                \
    }

#define READ_AF(slot, mh)                                                        \
    {                                                                            \
        _Pragma("unroll")                                                        \
        for (int mi = 0; mi < 4; ++mi) {                                         \
            int row = wm * 128 + (mh) * 64 + mi * 16 + l15;                      \
            unsigned o0 = (unsigned)(row * 128 + l4 * 16) ^ (unsigned)((row & 7) << 4); \
            af[mi][0] = *(const bf16x8*)((const char*)As[slot] + o0);            \
            af[mi][1] = *(const bf16x8*)((const char*)As[slot] + (o0 ^ 64u));    \
        }                                                                        \
    }

#define READ_BF(dst, slot, nh)                                                   \
    {                                                                            \
        _Pragma("unroll")                                                        \
        for (int ni = 0; ni < 2; ++ni) {                                         \
            int row = wn * 64 + (nh) * 32 + ni * 16 + l15;                       \
            unsigned o0 = (unsigned)(row * 128 + l4 * 16) ^ (unsigned)((row & 7) << 4); \
            dst[ni][0] = *(const bf16x8*)((const char*)Bs[slot] + o0);           \
            dst[ni][1] = *(const bf16x8*)((const char*)Bs[slot] + (o0 ^ 64u));   \
        }                                                                        \
    }

#define MFMA_Q(mlo, bb, nlo)                                                     \
    __builtin_amdgcn_s_setprio(1);                                               \
    _Pragma("unroll")                                                            \
    for (int kk = 0; kk < 2; ++kk) {                                             \
        _Pragma("unroll")                                                        \
        for (int mi = 0; mi < 4; ++mi) {                                         \
            _Pragma("unroll")                                                    \
            for (int ni = 0; ni < 2; ++ni)                                       \
                acc[(mlo) + mi][(nlo) + ni] = __builtin_amdgcn_mfma_f32_16x16x32_bf16( \
                    af[mi][kk], bb[ni][kk], acc[(mlo) + mi][(nlo) + ni], 0, 0, 0); \
        }                                                                        \
    }                                                                            \
    __builtin_amdgcn_s_setprio(0);

    // ---- prologue: kt0 -> slot0, kt1 -> slot1, full drain
    STAGE(As, Xp, 0, 0, 0);
    STAGE(As, Xp, 0, 1, 0);
    STAGE(Bs, Wp, 0, 0, 0);
    STAGE(Bs, Wp, 0, 1, 0);
    STAGE(As, Xp, 1, 0, 1);
    STAGE(As, Xp, 1, 1, 1);
    STAGE(Bs, Wp, 1, 0, 1);
    STAGE(Bs, Wp, 1, 1, 1);
    VMCNT0();
    BARRIER();

    // ---- main loop: 8 iterations x 2 K-tiles
    for (int it = 0; it < 8; ++it) {
        int c12 = 2 * it + 1;
        int c36 = (2 * it + 2 < 16) ? 2 * it + 2 : 15;
        int c78 = (2 * it + 3 < 16) ? 2 * it + 3 : 15;
        bf16x8 af[4][2], b0[2][2], b1[2][2];

        // P1
        READ_AF(0, 0); READ_BF(b0, 0, 0);
        STAGE(As, Xp, 1, 0, c12);
        BARRIER(); LGKM0(); SCHED0();
        MFMA_Q(0, b0, 0);
        BARRIER();

        // P2
        READ_BF(b1, 0, 1);
        STAGE(As, Xp, 1, 1, c12);
        BARRIER(); LGKM0(); SCHED0();
        MFMA_Q(0, b1, 2);
        BARRIER();

        // P3
        READ_AF(0, 1);
        STAGE(Bs, Wp, 0, 0, c36);
        BARRIER(); LGKM0(); SCHED0();
        MFMA_Q(4, b1, 2);
        BARRIER();

        // P4
        STAGE(Bs, Wp, 0, 1, c36);
        VMCNT4(); BARRIER(); SCHED0();
        MFMA_Q(4, b0, 0);
        BARRIER();

        // P5
        READ_AF(1, 0); READ_BF(b0, 1, 0);
        STAGE(As, Xp, 0, 0, c36);
        BARRIER(); LGKM0(); SCHED0();
        MFMA_Q(0, b0, 0);
        BARRIER();

        // P6
        READ_BF(b1, 1, 1);
        STAGE(As, Xp, 0, 1, c36);
        BARRIER(); LGKM0(); SCHED0();
        MFMA_Q(0, b1, 2);
        BARRIER();

        // P7
        READ_AF(1, 1);
        STAGE(Bs, Wp, 1, 0, c78);
        BARRIER(); LGKM0(); SCHED0();
        MFMA_Q(4, b1, 2);
        BARRIER();

        // P8
        STAGE(Bs, Wp, 1, 1, c78);
        VMCNT4(); BARRIER(); SCHED0();
        MFMA_Q(4, b0, 0);
        BARRIER();
    }
    VMCNT0();   // every wave's in-flight gloads landed
    BARRIER();  // LDS stable -> reuse as C-tile

    // ---- coalesced epilogue: 2 passes of 128 rows through As (64KB = [128][256])
    u16* Cs = &As[0][0];
#pragma unroll
    for (int p = 0; p < 2; ++p) {
        if (wm == p) {
#pragma unroll
            for (int ni = 0; ni < 4; ++ni) {
                float bv = bias[bn * 256 + wn * 64 + ni * 16 + l15];
#pragma unroll
                for (int mi = 0; mi < 8; ++mi) {
                    int lr0 = mi * 16 + l4 * 4;
                    int c   = wn * 64 + ni * 16 + l15;
#pragma unroll
                    for (int r = 0; r < 4; ++r)
                        Cs[(lr0 + r) * 256 + c] = f2bf(acc[mi][ni][r] + bv);
                }
            }
        }
        __syncthreads();
#pragma unroll
        for (int i = 0; i < 8; ++i) {
            int idx = tid + i * 512;          // 0..4095
            int row = idx >> 5;               // 0..127
            int c16 = idx & 31;               // 16B chunk
            ushort8v v = *(const ushort8v*)&Cs[row * 256 + c16 * 8];
            *(ushort8v*)&Y[(size_t)(bm * 256 + p * 128 + row) * KDIM
                           + bn * 256 + c16 * 8] = v;
        }
        __syncthreads();
    }

    // ---- overlapped tail: convert next projection's X (fp32 -> bf16).
    // Runs as each block finishes its GEMM work; hides the standalone 65us
    // cvt pass under GEMM block-tail skew + idle HBM bandwidth. Ordering to
    // the next GEMM dispatch is guaranteed by the stream dispatch boundary.
    if (Xbnext != nullptr) {
        unsigned n8 = (unsigned)((size_t)NROW * KDIM / 8);   // 8,388,608
        unsigned stride = gridDim.x * 512;
        for (unsigned i = (unsigned)bx * 512 + tid; i < n8; i += stride) {
            size_t base = (size_t)i * 8;
            vfloat4 a = *(const vfloat4*)(Xnext + base);
            vfloat4 b = *(const vfloat4*)(Xnext + base + 4);
            ushort8v o;
#pragma unroll
            for (int j = 0; j < 4; ++j) { o[j] = f2bf(a[j]); o[j + 4] = f2bf(b[j]); }
            *(ushort8v*)(Xbnext + base) = o;
        }
    }
#undef STAGE
#undef READ_AF
#undef READ_BF
#undef MFMA_Q
}

// ---------------- Fallback: fp32 in, convert in-loop (128^2, 2-barrier) -----
__global__ __launch_bounds__(256)
void proj_gemm(const float* __restrict__ X, const float* __restrict__ W,
               const float* __restrict__ bias, u16* __restrict__ Y)
{
    __shared__ u16 As[128 * 64];
    __shared__ u16 Bs[128 * 64];

    int bx = blockIdx.x;
    int wg = (bx & 7) * 512 + (bx >> 3);
    int bm = wg >> 3;
    int bn = wg & 7;

    int tid  = threadIdx.x;
    int lane = tid & 63;
    int wid  = tid >> 6;
    int wrow = (wid >> 1) * 64;
    int wcol = (wid & 1) * 64;
    int l15 = lane & 15;
    int l4  = lane >> 4;

    int srow = tid >> 4;
    int scol = (tid & 15) * 4;

    const float* Xp = X + (size_t)bm * 128 * KDIM;
    const float* Wp = W + (size_t)bn * 128 * KDIM;

    f32x4 acc[4][4] = {};

    for (int k0 = 0; k0 < KDIM; k0 += 64) {
        __syncthreads();
#pragma unroll
        for (int r = 0; r < 8; ++r) {
            int row = r * 16 + srow;
            vfloat4 a = *(const vfloat4*)(Xp + (size_t)row * KDIM + k0 + scol);
            vfloat4 b = *(const vfloat4*)(Wp + (size_t)row * KDIM + k0 + scol);
            ushort4v ap, bp;
#pragma unroll
            for (int j = 0; j < 4; ++j) { ap[j] = f2bf(a[j]); bp[j] = f2bf(b[j]); }
            unsigned off = (unsigned)(row * 128 + scol * 2) ^ (unsigned)((row & 7) << 4);
            *(ushort4v*)((char*)As + off) = ap;
            *(ushort4v*)((char*)Bs + off) = bp;
        }
        __syncthreads();
#pragma unroll
        for (int kk = 0; kk < 2; ++kk) {
            bf16x8 af[4], bfr[4];
#pragma unroll
            for (int mi = 0; mi < 4; ++mi) {
                int row = wrow + mi * 16 + l15;
                unsigned off = (unsigned)(row * 128 + kk * 64 + l4 * 16) ^ (unsigned)((row & 7) << 4);
                af[mi] = *(const bf16x8*)((char*)As + off);
            }
#pragma unroll
            for (int ni = 0; ni < 4; ++ni) {
                int row = wcol + ni * 16 + l15;
                unsigned off = (unsigned)(row * 128 + kk * 64 + l4 * 16) ^ (unsigned)((row & 7) << 4);
                bfr[ni] = *(const bf16x8*)((char*)Bs + off);
            }
#pragma unroll
            for (int mi = 0; mi < 4; ++mi)
#pragma unroll
                for (int ni = 0; ni < 4; ++ni)
                    acc[mi][ni] = __builtin_amdgcn_mfma_f32_16x16x32_bf16(
                        af[mi], bfr[ni], acc[mi][ni], 0, 0, 0);
        }
    }

#pragma unroll
    for (int ni = 0; ni < 4; ++ni) {
        int col = bn * 128 + wcol + ni * 16 + l15;
        float bv = bias[col];
#pragma unroll
        for (int mi = 0; mi < 4; ++mi) {
            int row0 = bm * 128 + wrow + mi * 16 + l4 * 4;
#pragma unroll
            for (int r = 0; r < 4; ++r)
                Y[(size_t)(row0 + r) * KDIM + col] = f2bf(acc[mi][ni][r] + bv);
        }
    }
}

// ---------------- Pass 2: grouped attention ----------------
__global__ __launch_bounds__(256)
void attn_kernel(const u16* __restrict__ Qg, const u16* __restrict__ Kg,
                 const u16* __restrict__ Vg, float* __restrict__ Out)
{
    __shared__ u16 Qs[128 * 64];     // [q][d] swizzled
    __shared__ u16 KVs[64 * 136];    // union: Ks [128][64] swizzled / Vt [64][136]
    __shared__ u16 Ps[128 * 136];    // [q][k], row stride 136

    int g = blockIdx.x >> 4;
    int h = blockIdx.x & 15;

    int tid  = threadIdx.x;
    int lane = tid & 63;
    int wid  = tid >> 6;
    int l15 = lane & 15, l4 = lane >> 4;
    int qbase = wid * 32;

    size_t rowbase = (size_t)g * 128 * 1024 + (size_t)h * 64;

    {
        int r  = tid >> 1;
        int c0 = (tid & 1) * 32;
        const u16* qsrc = Qg + rowbase + (size_t)r * 1024 + c0;
        const u16* ksrc = Kg + rowbase + (size_t)r * 1024 + c0;
#pragma unroll
        for (int i = 0; i < 4; ++i) {
            ushort8v qv = *(const ushort8v*)(qsrc + i * 8);
            ushort8v kv = *(const ushort8v*)(ksrc + i * 8);
            unsigned off = (unsigned)(r * 128 + (c0 + i * 8) * 2) ^ (unsigned)((r & 7) << 4);
            *(ushort8v*)((char*)Qs + off) = qv;
            *(ushort8v*)((char*)KVs + off) = kv;
        }
    }
    __syncthreads();

    f32x4 st[8][2] = {};
#pragma unroll
    for (int kk = 0; kk < 2; ++kk) {
        bf16x8 kf[8];
#pragma unroll
        for (int mi = 0; mi < 8; ++mi) {
            int row = mi * 16 + l15;
            unsigned off = (unsigned)(row * 128 + kk * 64 + l4 * 16) ^ (unsigned)((row & 7) << 4);
            kf[mi] = *(const bf16x8*)((char*)KVs + off);
        }
#pragma unroll
        for (int qi = 0; qi < 2; ++qi) {
            int row = qbase + qi * 16 + l15;
            unsigned off = (unsigned)(row * 128 + kk * 64 + l4 * 16) ^ (unsigned)((row & 7) << 4);
            bf16x8 qf = *(const bf16x8*)((char*)Qs + off);
#pragma unroll
            for (int mi = 0; mi < 8; ++mi)
                st[mi][qi] = __builtin_amdgcn_mfma_f32_16x16x32_bf16(kf[mi], qf, st[mi][qi], 0, 0, 0);
        }
    }
    __syncthreads();

    {
        int r  = tid >> 1;
        int c0 = (tid & 1) * 32;
        const u16* vsrc = Vg + rowbase + (size_t)r * 1024 + c0;
#pragma unroll
        for (int i = 0; i < 4; ++i) {
            ushort8v vv = *(const ushort8v*)(vsrc + i * 8);
#pragma unroll
            for (int e = 0; e < 8; ++e)
                KVs[(c0 + i * 8 + e) * 136 + r] = vv[e];
        }
    }

    const float cexp = 0.125f * 1.44269504088896f;
#pragma unroll
    for (int qi = 0; qi < 2; ++qi) {
        float m = -3.0e38f;
#pragma unroll
        for (int mi = 0; mi < 8; ++mi)
#pragma unroll
            for (int r = 0; r < 4; ++r) m = fmaxf(m, st[mi][qi][r]);
        m = fmaxf(m, __shfl_xor(m, 16));
        m = fmaxf(m, __shfl_xor(m, 32));
        float s = 0.f;
#pragma unroll
        for (int mi = 0; mi < 8; ++mi)
#pragma unroll
            for (int r = 0; r < 4; ++r) {
                float p = exp2f((st[mi][qi][r] - m) * cexp);
                st[mi][qi][r] = p;
                s += p;
            }
        s += __shfl_xor(s, 16);
        s += __shfl_xor(s, 32);
        float inv = 1.0f / s;
        int q = qbase + qi * 16 + l15;
#pragma unroll
        for (int mi = 0; mi < 8; ++mi) {
            ushort4v pp;
#pragma unroll
            for (int r = 0; r < 4; ++r) pp[r] = f2bf(st[mi][qi][r] * inv);
            *(ushort4v*)((char*)Ps + (unsigned)(q * 272 + mi * 32 + l4 * 8)) = pp;
        }
    }
    __syncthreads();

    f32x4 o[2][4] = {};
#pragma unroll
    for (int kk = 0; kk < 4; ++kk) {
        bf16x8 pa[2];
#pragma unroll
        for (int mf = 0; mf < 2; ++mf) {
            int q = qbase + mf * 16 + l15;
            pa[mf] = *(const bf16x8*)((char*)Ps + (unsigned)(q * 272 + kk * 64 + l4 * 16));
        }
#pragma unroll
        for (int nf = 0; nf < 4; ++nf) {
            int d = nf * 16 + l15;
            bf16x8 vb = *(const bf16x8*)((char*)KVs + (unsigned)(d * 272 + kk * 64 + l4 * 16));
#pragma unroll
            for (int mf = 0; mf < 2; ++mf)
                o[mf][nf] = __builtin_amdgcn_mfma_f32_16x16x32_bf16(pa[mf], vb, o[mf][nf], 0, 0, 0);
        }
    }

#pragma unroll
    for (int mf = 0; mf < 2; ++mf)
#pragma unroll
        for (int nf = 0; nf < 4; ++nf) {
            int d  = nf * 16 + l15;
            int q0 = qbase + mf * 16 + l4 * 4;
#pragma unroll
            for (int r = 0; r < 4; ++r)
                Out[(size_t)(g * 128 + q0 + r) * 1024 + h * 64 + d] = o[mf][nf][r];
        }
}

extern "C" void kernel_launch(void* const* d_in, const int* in_sizes, int n_in,
                              void* d_out, int out_size, void* d_ws, size_t ws_size,
                              hipStream_t stream)
{
    const float* Xq = (const float*)d_in[0];
    const float* Xk = (const float*)d_in[1];
    const float* Xv = (const float*)d_in[2];
    const float* Wq = (const float*)d_in[3];
    const float* bq = (const float*)d_in[4];
    const float* Wk = (const float*)d_in[5];
    const float* bk = (const float*)d_in[6];
    const float* Wv = (const float*)d_in[7];
    const float* bv = (const float*)d_in[8];

    const size_t NE = (size_t)NROW * KDIM;       // 67,108,864
    const size_t WE = (size_t)KDIM * KDIM;       // 1,048,576

    u16* Qw = (u16*)d_ws;
    u16* Kw = Qw + NE;
    u16* Vw = Kw + NE;

    size_t need2 = NE * 2 * 3 + NE * 2 * 2 + WE * 2 * 3;  // QKV + 2 Xb + 3 W
    size_t need1 = NE * 2 * 3 + NE * 2     + WE * 2 * 3;  // QKV + 1 Xb + 3 W

    if (ws_size >= need2) {
        // overlapped path: cvt of X(k+1) rides in GEMM(k)'s tail
        u16* Xb0 = Vw + NE;
        u16* Xb1 = Xb0 + NE;
        u16* Wb0 = Xb1 + NE;
        u16* Wb1 = Wb0 + WE;
        u16* Wb2 = Wb1 + WE;

        cvt_f32_bf16<<<dim3(512),  dim3(256), 0, stream>>>(Wq, Wb0, (unsigned)(WE / 8));
        cvt_f32_bf16<<<dim3(512),  dim3(256), 0, stream>>>(Wk, Wb1, (unsigned)(WE / 8));
        cvt_f32_bf16<<<dim3(512),  dim3(256), 0, stream>>>(Wv, Wb2, (unsigned)(WE / 8));
        cvt_f32_bf16<<<dim3(2048), dim3(256), 0, stream>>>(Xq, Xb0, (unsigned)(NE / 8));

        proj_gemm_8ph<<<dim3(1024), dim3(512), 0, stream>>>(Xb0, Wb0, bq, Qw, Xk, Xb1);
        proj_gemm_8ph<<<dim3(1024), dim3(512), 0, stream>>>(Xb1, Wb1, bk, Kw, Xv, Xb0);
        proj_gemm_8ph<<<dim3(1024), dim3(512), 0, stream>>>(Xb0, Wb2, bv, Vw, nullptr, nullptr);
    } else if (ws_size >= need1) {
        u16* Xb  = Vw + NE;
        u16* Wb0 = Xb + NE;
        u16* Wb1 = Wb0 + WE;
        u16* Wb2 = Wb1 + WE;

        cvt_f32_bf16<<<dim3(512),  dim3(256), 0, stream>>>(Wq, Wb0, (unsigned)(WE / 8));
        cvt_f32_bf16<<<dim3(512),  dim3(256), 0, stream>>>(Wk, Wb1, (unsigned)(WE / 8));
        cvt_f32_bf16<<<dim3(512),  dim3(256), 0, stream>>>(Wv, Wb2, (unsigned)(WE / 8));

        cvt_f32_bf16<<<dim3(2048), dim3(256), 0, stream>>>(Xq, Xb, (unsigned)(NE / 8));
        proj_gemm_8ph<<<dim3(1024), dim3(512), 0, stream>>>(Xb, Wb0, bq, Qw, nullptr, nullptr);
        cvt_f32_bf16<<<dim3(2048), dim3(256), 0, stream>>>(Xk, Xb, (unsigned)(NE / 8));
        proj_gemm_8ph<<<dim3(1024), dim3(512), 0, stream>>>(Xb, Wb1, bk, Kw, nullptr, nullptr);
        cvt_f32_bf16<<<dim3(2048), dim3(256), 0, stream>>>(Xv, Xb, (unsigned)(NE / 8));
        proj_gemm_8ph<<<dim3(1024), dim3(512), 0, stream>>>(Xb, Wb2, bv, Vw, nullptr, nullptr);
    } else {
        proj_gemm<<<dim3(4096), dim3(256), 0, stream>>>(Xq, Wq, bq, Qw);
        proj_gemm<<<dim3(4096), dim3(256), 0, stream>>>(Xk, Wk, bk, Kw);
        proj_gemm<<<dim3(4096), dim3(256), 0, stream>>>(Xv, Wv, bv, Vw);
    }

    attn_kernel<<<dim3(512 * 16), dim3(256), 0, stream>>>(Qw, Kw, Vw, (float*)d_out);
}